// Round 8
// baseline (778.488 us; speedup 1.0000x reference)
//
#include <hip/hip_runtime.h>
#include <hip/hip_cooperative_groups.h>

namespace cg = cooperative_groups;

#define NN 10000
#define NE 640000
#define NB 313          // buckets of 32 nodes; also # partition vblocks
#define RSTRIDE 2688    // slots per bucket (mean 2045, sigma~45)
#define EPB 2048        // edges per partition vblock
#define G1B 1250        // gemm1 vblocks (8 rows each)
#define G1_SPLIT 625    // gemm1 vblocks done in P1; rest in P2

__device__ __forceinline__ unsigned short f2bf(float x) {   // RNE
    unsigned u = __float_as_uint(x);
    u += 0x7FFFu + ((u >> 16) & 1u);
    return (unsigned short)(u >> 16);
}
__device__ __forceinline__ float bflo(unsigned u) { return __uint_as_float(u << 16); }
__device__ __forceinline__ float bfhi(unsigned u) { return __uint_as_float(u & 0xFFFF0000u); }
__device__ __forceinline__ float bf1(unsigned short h) { return __uint_as_float((unsigned)h << 16); }

struct SMpart { int hist[NB]; int scanv[NB + 1]; int gbase[NB]; int lcur[NB];
                unsigned stage[EPB]; };
struct SMbuild { int sbase[NB + 1]; int hist32[32]; int cur32[32];
                 unsigned stage[RSTRIDE]; };
union SMu {
    SMpart p;
    SMbuild b;
    float xs[16][128];
    float2 red2[3][64];
    float red1[3][64];
};

// ---- gemm1: 8 rows of Y = X[f32] @ W[128x128] -> bf16 ----
__device__ __forceinline__ void gemm1_block(const float* __restrict__ X,
                                            const float* __restrict__ W,
                                            unsigned short* Y, float (*xs)[128],
                                            int vb, int tid) {
    int row0 = vb * 8;
    for (int idx = tid; idx < 8 * 128; idx += 256) {
        int r = idx >> 7, k = idx & 127;
        xs[r][k] = X[(size_t)(row0 + r) * 128 + k];
    }
    __syncthreads();
    int ct = tid & 31, r = tid >> 5, c = ct * 4;
    float4 acc = make_float4(0.f, 0.f, 0.f, 0.f);
    #pragma unroll 8
    for (int k = 0; k < 128; ++k) {
        float xv = xs[r][k];
        float4 w = *reinterpret_cast<const float4*>(W + (size_t)k * 128 + c);
        acc.x += xv * w.x; acc.y += xv * w.y; acc.z += xv * w.z; acc.w += xv * w.w;
    }
    ushort4 o;
    o.x = f2bf(acc.x); o.y = f2bf(acc.y); o.z = f2bf(acc.z); o.w = f2bf(acc.w);
    *reinterpret_cast<ushort4*>(Y + (size_t)(row0 + r) * 128 + c) = o;
}

// ---- bf16-in GEMM: ROWS rows, NOUTc cols ----
template<int NOUTc, int ROWS>
__device__ __forceinline__ void gemm_bf_block(const unsigned short* Xb,
                                              const float* __restrict__ W,
                                              unsigned short* Y, float (*xs)[128],
                                              int vb, int tid) {
    int row0 = vb * ROWS;
    const unsigned* Xu = reinterpret_cast<const unsigned*>(Xb + (size_t)row0 * 128);
    for (int idx = tid; idx < ROWS * 64; idx += 256) {
        unsigned u = Xu[idx];
        int r = idx >> 6, kk = idx & 63;
        xs[r][kk * 2]     = bflo(u);
        xs[r][kk * 2 + 1] = bfhi(u);
    }
    __syncthreads();
    constexpr int COLT = NOUTc / 4;
    int ct = tid % COLT, r = tid / COLT, c = ct * 4;
    float4 acc = make_float4(0.f, 0.f, 0.f, 0.f);
    #pragma unroll 8
    for (int k = 0; k < 128; ++k) {
        float xv = xs[r][k];
        float4 w = *reinterpret_cast<const float4*>(W + (size_t)k * NOUTc + c);
        acc.x += xv * w.x; acc.y += xv * w.y; acc.z += xv * w.z; acc.w += xv * w.w;
    }
    ushort4 o;
    o.x = f2bf(acc.x); o.y = f2bf(acc.y); o.z = f2bf(acc.z); o.w = f2bf(acc.w);
    *reinterpret_cast<ushort4*>(Y + (size_t)(row0 + r) * NOUTc + c) = o;
}

// ---- partition: one vblock of EPB edges -> bucketed records ----
__device__ __forceinline__ void partition_block(const int* __restrict__ src,
                                                const int* __restrict__ dst,
                                                int* __restrict__ bcur,
                                                unsigned* edge_part,
                                                SMpart& p, int bid, int tid) {
    for (int i = tid; i < NB; i += 256) p.hist[i] = 0;
    __syncthreads();
    int gi = bid * EPB + tid * 8;
    unsigned rec[8];
    bool act = gi < NE;
    if (act) {
        int4 s0 = *reinterpret_cast<const int4*>(src + gi);
        int4 s1 = *reinterpret_cast<const int4*>(src + gi + 4);
        int4 d0 = *reinterpret_cast<const int4*>(dst + gi);
        int4 d1 = *reinterpret_cast<const int4*>(dst + gi + 4);
        rec[0] = ((unsigned)d0.x << 14) | (unsigned)s0.x;
        rec[1] = ((unsigned)d0.y << 14) | (unsigned)s0.y;
        rec[2] = ((unsigned)d0.z << 14) | (unsigned)s0.z;
        rec[3] = ((unsigned)d0.w << 14) | (unsigned)s0.w;
        rec[4] = ((unsigned)d1.x << 14) | (unsigned)s1.x;
        rec[5] = ((unsigned)d1.y << 14) | (unsigned)s1.y;
        rec[6] = ((unsigned)d1.z << 14) | (unsigned)s1.z;
        rec[7] = ((unsigned)d1.w << 14) | (unsigned)s1.w;
        #pragma unroll
        for (int k = 0; k < 8; ++k) atomicAdd(&p.hist[rec[k] >> 19], 1);
    }
    __syncthreads();
    if (tid < 64) {          // wave-0 exclusive scan of hist
        int carry = 0;
        for (int c = 0; c < NB; c += 64) {
            int idx = c + tid;
            int v = (idx < NB) ? p.hist[idx] : 0;
            int incl = v;
            #pragma unroll
            for (int d = 1; d < 64; d <<= 1) {
                int t = __shfl_up(incl, d, 64);
                if (tid >= d) incl += t;
            }
            if (idx < NB) p.scanv[idx] = carry + incl - v;
            carry += __shfl(incl, 63, 64);
        }
        if (tid == 0) p.scanv[NB] = carry;
    }
    __syncthreads();
    for (int bb = tid; bb < NB; bb += 256) {
        p.gbase[bb] = atomicAdd(&bcur[bb], p.hist[bb]);
        p.lcur[bb]  = p.scanv[bb];
    }
    __syncthreads();
    if (act) {
        #pragma unroll
        for (int k = 0; k < 8; ++k) {
            int bb = rec[k] >> 19;
            int pp = atomicAdd(&p.lcur[bb], 1);
            p.stage[pp] = rec[k];
        }
    }
    __syncthreads();
    int tot = p.scanv[NB];
    for (int i = tid; i < tot; i += 256) {
        unsigned r = p.stage[i];
        int bb = r >> 19;
        edge_part[bb * RSTRIDE + p.gbase[bb] + (i - p.scanv[bb])] = r;
    }
}

// ---- build: one bucket -> offs/inv_sqrt + node-sorted CSR ----
__device__ __forceinline__ void build_block(const unsigned* edge_part,
                                            const int* __restrict__ bcur,
                                            int* __restrict__ offs,
                                            float* __restrict__ inv_sqrt,
                                            int* __restrict__ edge_src,
                                            SMbuild& b, int bid, int tid) {
    if (tid < 64) {
        int carry = 0;
        for (int c = 0; c < NB; c += 64) {
            int idx = c + tid;
            int v = (idx < NB) ? bcur[idx] : 0;
            int incl = v;
            #pragma unroll
            for (int d = 1; d < 64; d <<= 1) {
                int t = __shfl_up(incl, d, 64);
                if (tid >= d) incl += t;
            }
            if (idx < NB) b.sbase[idx] = carry + incl - v;
            carry += __shfl(incl, 63, 64);
        }
    }
    if (tid < 32) b.hist32[tid] = 0;
    __syncthreads();
    int cnt = bcur[bid];
    int base = b.sbase[bid];
    const unsigned* part = edge_part + (size_t)bid * RSTRIDE;
    for (int k = tid; k < cnt; k += 256)
        atomicAdd(&b.hist32[(part[k] >> 14) & 31], 1);
    __syncthreads();
    if (tid < 32) {
        int v = b.hist32[tid];
        int incl = v;
        #pragma unroll
        for (int d = 1; d < 32; d <<= 1) {
            int t = __shfl_up(incl, d, 32);
            if (tid >= d) incl += t;
        }
        int excl = incl - v;
        b.cur32[tid] = excl;
        int node = bid * 32 + tid;
        if (node < NN) {
            offs[node] = base + excl;
            inv_sqrt[node] = rsqrtf((float)(v + 1));
        }
        if (bid == NB - 1 && tid == 0) offs[NN] = base + cnt;
    }
    __syncthreads();
    for (int k = tid; k < cnt; k += 256) {
        unsigned r = part[k];
        int pp = atomicAdd(&b.cur32[(r >> 14) & 31], 1);
        b.stage[pp] = r & 0x3FFFu;
    }
    __syncthreads();
    for (int k = tid; k < cnt; k += 256)
        edge_src[base + k] = (int)b.stage[k];
}

// ---- agg128: one node with 4 waves; bf16 out packed as unsigned ----
__device__ __forceinline__ void agg128_node(const unsigned short* H, unsigned* Aout,
                                            float bx, float by,
                                            const int* __restrict__ offs,
                                            const float* __restrict__ isqv,
                                            const int* __restrict__ esrc,
                                            float2 (*red)[64], int node,
                                            int lane, int wv) {
    int s = offs[node], e = offs[node + 1];
    int deg = e - s;
    int qlen = (((deg + 3) >> 2) + 3) & ~3;
    int js = s + wv * qlen;
    int je = js + qlen;
    if (js > e) js = e;
    if (je > e) je = e;
    int col = lane * 2;
    float2 acc = make_float2(0.f, 0.f);
    int j = js;
    for (; j + 4 <= je; j += 4) {
        int s0 = esrc[j], s1 = esrc[j + 1], s2 = esrc[j + 2], s3 = esrc[j + 3];
        float w0 = isqv[s0], w1 = isqv[s1], w2 = isqv[s2], w3 = isqv[s3];
        unsigned u0 = *reinterpret_cast<const unsigned*>(H + (size_t)s0 * 128 + col);
        unsigned u1 = *reinterpret_cast<const unsigned*>(H + (size_t)s1 * 128 + col);
        unsigned u2 = *reinterpret_cast<const unsigned*>(H + (size_t)s2 * 128 + col);
        unsigned u3 = *reinterpret_cast<const unsigned*>(H + (size_t)s3 * 128 + col);
        acc.x += w0 * bflo(u0); acc.y += w0 * bfhi(u0);
        acc.x += w1 * bflo(u1); acc.y += w1 * bfhi(u1);
        acc.x += w2 * bflo(u2); acc.y += w2 * bfhi(u2);
        acc.x += w3 * bflo(u3); acc.y += w3 * bfhi(u3);
    }
    for (; j < je; ++j) {
        int s0 = esrc[j];
        float w0 = isqv[s0];
        unsigned u0 = *reinterpret_cast<const unsigned*>(H + (size_t)s0 * 128 + col);
        acc.x += w0 * bflo(u0); acc.y += w0 * bfhi(u0);
    }
    if (wv) red[wv - 1][lane] = acc;
    __syncthreads();
    if (!wv) {
        acc.x += red[0][lane].x + red[1][lane].x + red[2][lane].x;
        acc.y += red[0][lane].y + red[1][lane].y + red[2][lane].y;
        float isq = isqv[node];
        unsigned uv = *reinterpret_cast<const unsigned*>(H + (size_t)node * 128 + col);
        float self = isq * isq;
        float ox = fmaxf(acc.x * isq + self * bflo(uv) + bx, 0.f);
        float oy = fmaxf(acc.y * isq + self * bfhi(uv) + by, 0.f);
        Aout[(size_t)node * 64 + lane] = (unsigned)f2bf(ox) | ((unsigned)f2bf(oy) << 16);
    }
    __syncthreads();
}

// ---- agg64: one node with 4 waves; f32 out, no relu ----
__device__ __forceinline__ void agg64_node(const unsigned short* H,
                                           float* __restrict__ out, float b3v,
                                           const int* __restrict__ offs,
                                           const float* __restrict__ isqv,
                                           const int* __restrict__ esrc,
                                           float (*red)[64], int node,
                                           int lane, int wv) {
    int s = offs[node], e = offs[node + 1];
    int deg = e - s;
    int qlen = (((deg + 3) >> 2) + 3) & ~3;
    int js = s + wv * qlen;
    int je = js + qlen;
    if (js > e) js = e;
    if (je > e) je = e;
    float acc = 0.f;
    int j = js;
    for (; j + 4 <= je; j += 4) {
        int s0 = esrc[j], s1 = esrc[j + 1], s2 = esrc[j + 2], s3 = esrc[j + 3];
        float w0 = isqv[s0], w1 = isqv[s1], w2 = isqv[s2], w3 = isqv[s3];
        acc += w0 * bf1(H[(size_t)s0 * 64 + lane]);
        acc += w1 * bf1(H[(size_t)s1 * 64 + lane]);
        acc += w2 * bf1(H[(size_t)s2 * 64 + lane]);
        acc += w3 * bf1(H[(size_t)s3 * 64 + lane]);
    }
    for (; j < je; ++j) {
        int s0 = esrc[j];
        acc += isqv[s0] * bf1(H[(size_t)s0 * 64 + lane]);
    }
    if (wv) red[wv - 1][lane] = acc;
    __syncthreads();
    if (!wv) {
        acc += red[0][lane] + red[1][lane] + red[2][lane];
        float isq = isqv[node];
        float hv = bf1(H[(size_t)node * 64 + lane]);
        out[(size_t)node * 64 + lane] = acc * isq + isq * isq * hv + b3v;
    }
    __syncthreads();
}

// ======================= cooperative megakernel =======================
__global__ __launch_bounds__(256, 4) void mega_kernel(
        const int* __restrict__ src, const int* __restrict__ dst,
        const float* __restrict__ X,
        const float* __restrict__ W1, const float* __restrict__ b1,
        const float* __restrict__ W2, const float* __restrict__ b2,
        const float* __restrict__ W3, const float* __restrict__ b3,
        int* __restrict__ bcur, unsigned* edge_part,
        int* __restrict__ offs, float* __restrict__ inv_sqrt,
        int* __restrict__ edge_src,
        unsigned short* T1, unsigned short* A,
        unsigned short* T2, unsigned short* T3,
        float* __restrict__ out) {
    cg::grid_group grid = cg::this_grid();
    __shared__ SMu sm;
    const int tid = threadIdx.x;
    const int bid = blockIdx.x;
    const int nblk = gridDim.x;
    const int lane = tid & 63, wv = tid >> 6;

    // P0: zero bucket counters
    for (int g = bid * 256 + tid; g < NB; g += nblk * 256) bcur[g] = 0;
    grid.sync();

    // P1: partition (blocks 0..NB) || gemm1 first half
    if (bid < NB) {
        partition_block(src, dst, bcur, edge_part, sm.p, bid, tid);
    } else {
        for (int vb = bid - NB; vb < G1_SPLIT; vb += nblk - NB) {
            gemm1_block(X, W1, T1, sm.xs, vb, tid);
            __syncthreads();
        }
    }
    grid.sync();

    // P2: build (blocks 0..NB) || gemm1 second half
    if (bid < NB) {
        build_block(edge_part, bcur, offs, inv_sqrt, edge_src, sm.b, bid, tid);
    } else {
        for (int vb = G1_SPLIT + (bid - NB); vb < G1B; vb += nblk - NB) {
            gemm1_block(X, W1, T1, sm.xs, vb, tid);
            __syncthreads();
        }
    }
    grid.sync();

    // P3: layer-1 aggregation
    {
        int col = lane * 2;
        float bx = b1[col], by = b1[col + 1];
        for (int node = bid; node < NN; node += nblk)
            agg128_node(T1, (unsigned*)A, bx, by, offs, inv_sqrt, edge_src,
                        sm.red2, node, lane, wv);
    }
    grid.sync();

    // P4: gemm2
    for (int vb = bid; vb < G1B; vb += nblk) {
        gemm_bf_block<128, 8>(A, W2, T2, sm.xs, vb, tid);
        __syncthreads();
    }
    grid.sync();

    // P5: layer-2 aggregation
    {
        int col = lane * 2;
        float bx = b2[col], by = b2[col + 1];
        for (int node = bid; node < NN; node += nblk)
            agg128_node(T2, (unsigned*)A, bx, by, offs, inv_sqrt, edge_src,
                        sm.red2, node, lane, wv);
    }
    grid.sync();

    // P6: gemm3
    for (int vb = bid; vb < NN / 16; vb += nblk) {
        gemm_bf_block<64, 16>(A, W3, T3, sm.xs, vb, tid);
        __syncthreads();
    }
    grid.sync();

    // P7: final 64-ch aggregation
    {
        float b3v = b3[lane];
        for (int node = bid; node < NN; node += nblk)
            agg64_node(T3, out, b3v, offs, inv_sqrt, edge_src,
                       sm.red1, node, lane, wv);
    }
}

// ======================= fallback multi-kernel path =======================
__global__ __launch_bounds__(256) void part_gemm1_kernel(
        const int* __restrict__ src, const int* __restrict__ dst,
        int* __restrict__ bcur, unsigned* __restrict__ edge_part,
        const float* __restrict__ X, const float* __restrict__ W,
        unsigned short* __restrict__ Y) {
    __shared__ SMu sm;
    int tid = threadIdx.x;
    if (blockIdx.x >= NB) {
        gemm1_block(X, W, Y, sm.xs, blockIdx.x - NB, tid);
        return;
    }
    partition_block(src, dst, bcur, edge_part, sm.p, blockIdx.x, tid);
}

__global__ __launch_bounds__(256) void build_kernel(
        const unsigned* __restrict__ edge_part, const int* __restrict__ bcur,
        int* __restrict__ offs, float* __restrict__ inv_sqrt,
        int* __restrict__ edge_src) {
    __shared__ SMu sm;
    build_block(edge_part, bcur, offs, inv_sqrt, edge_src, sm.b,
                blockIdx.x, threadIdx.x);
}

__global__ __launch_bounds__(256) void agg128_kernel(
        const unsigned short* __restrict__ H, const int* __restrict__ esrc,
        const int* __restrict__ offs, const float* __restrict__ inv_sqrt,
        const float* __restrict__ bias, unsigned* __restrict__ Aout) {
    __shared__ SMu sm;
    int tid = threadIdx.x, lane = tid & 63, wv = tid >> 6;
    int col = lane * 2;
    agg128_node(H, Aout, bias[col], bias[col + 1], offs, inv_sqrt, esrc,
                sm.red2, blockIdx.x, lane, wv);
}

__global__ __launch_bounds__(256) void agg64_kernel(
        const unsigned short* __restrict__ H, const int* __restrict__ esrc,
        const int* __restrict__ offs, const float* __restrict__ inv_sqrt,
        const float* __restrict__ bias, float* __restrict__ out) {
    __shared__ SMu sm;
    int tid = threadIdx.x, lane = tid & 63, wv = tid >> 6;
    agg64_node(H, out, bias[lane], offs, inv_sqrt, esrc,
               sm.red1, blockIdx.x, lane, wv);
}

template<int N>
__global__ __launch_bounds__(256) void gemm_bf_kernel(
        const unsigned short* __restrict__ X, const float* __restrict__ W,
        unsigned short* __restrict__ Y) {
    __shared__ SMu sm;
    gemm_bf_block<N, 256 / (N / 4)>(X, W, Y, sm.xs, blockIdx.x, threadIdx.x);
}

extern "C" void kernel_launch(void* const* d_in, const int* in_sizes, int n_in,
                              void* d_out, int out_size, void* d_ws, size_t ws_size,
                              hipStream_t stream) {
    const float* x  = (const float*)d_in[0];
    const int*   ei = (const int*)d_in[1];
    const float* W1 = (const float*)d_in[2];
    const float* b1 = (const float*)d_in[3];
    const float* W2 = (const float*)d_in[4];
    const float* b2 = (const float*)d_in[5];
    const float* W3 = (const float*)d_in[6];
    const float* b3 = (const float*)d_in[7];
    float* out = (float*)d_out;

    const int* src = ei;
    const int* dst = ei + NE;

    char* ws = (char*)d_ws;
    int*            bcur      = (int*)(ws);                        // 1,252 B
    float*          inv_sqrt  = (float*)(ws + 4096);               // 40,000 B
    int*            offs      = (int*)(ws + 45056);                // 40,004 B
    unsigned*       edge_part = (unsigned*)(ws + 86016);           // 3,365,376 B
    int*            edge_src  = (int*)(ws + 3451392);              // 2,560,000 B
    unsigned short* T1        = (unsigned short*)(ws + 6011392);   // 2,560,000 B
    unsigned short* A         = (unsigned short*)(ws + 8571392);   // 2,560,000 B
    unsigned short* T2        = (unsigned short*)edge_part;        // alias (dead after build)
    unsigned short* T3        = T1;                                // alias (dead after agg1)

    // size the cooperative grid from the runtime's own occupancy calc
    int maxb = 0;
    hipError_t oe = hipOccupancyMaxActiveBlocksPerMultiprocessor(&maxb, mega_kernel,
                                                                 256, 0);
    int nblk = (oe == hipSuccess) ? maxb * 256 : 0;   // 256 CUs on MI355X
    if (nblk > 1024) nblk = 1024;

    bool coop_ok = false;
    if (nblk >= 512) {
        void* args[] = {
            (void*)&src, (void*)&dst, (void*)&x,
            (void*)&W1, (void*)&b1, (void*)&W2, (void*)&b2, (void*)&W3, (void*)&b3,
            (void*)&bcur, (void*)&edge_part, (void*)&offs, (void*)&inv_sqrt,
            (void*)&edge_src, (void*)&T1, (void*)&A, (void*)&T2, (void*)&T3,
            (void*)&out
        };
        hipError_t err = hipLaunchCooperativeKernel(mega_kernel, dim3(nblk), dim3(256),
                                                    args, 0, stream);
        coop_ok = (err == hipSuccess);
    }

    if (!coop_ok) {   // proven multi-kernel path (round 6)
        hipMemsetAsync(bcur, 0, NB * sizeof(int), stream);
        part_gemm1_kernel<<<NB + G1B, 256, 0, stream>>>(src, dst, bcur, edge_part,
                                                        x, W1, T1);
        build_kernel<<<NB, 256, 0, stream>>>(edge_part, bcur, offs, inv_sqrt, edge_src);
        agg128_kernel<<<NN, 256, 0, stream>>>(T1, edge_src, offs, inv_sqrt, b1,
                                              (unsigned*)A);
        gemm_bf_kernel<128><<<NN / 8, 256, 0, stream>>>(A, W2, T2);
        agg128_kernel<<<NN, 256, 0, stream>>>(T2, edge_src, offs, inv_sqrt, b2,
                                              (unsigned*)A);
        gemm_bf_kernel<64><<<NN / 16, 256, 0, stream>>>(A, W3, T3);
        agg64_kernel<<<NN, 256, 0, stream>>>(T3, edge_src, offs, inv_sqrt, b3, out);
    }
}

// Round 9
// 148.992 us; speedup vs baseline: 5.2250x; 5.2250x over previous
//
#include <hip/hip_runtime.h>

#define NN 10000
#define NE 640000
#define NB 313          // buckets of 32 nodes; also # partition vblocks
#define RSTRIDE 2688    // slots per bucket (mean 2045, sigma~45)
#define EPB 2048        // edges per partition vblock
#define G1B 1250        // gemm1 vblocks (8 rows each)

__device__ __forceinline__ unsigned short f2bf(float x) {   // RNE
    unsigned u = __float_as_uint(x);
    u += 0x7FFFu + ((u >> 16) & 1u);
    return (unsigned short)(u >> 16);
}
__device__ __forceinline__ float bflo(unsigned u) { return __uint_as_float(u << 16); }
__device__ __forceinline__ float bfhi(unsigned u) { return __uint_as_float(u & 0xFFFF0000u); }
__device__ __forceinline__ float bf1(unsigned short h) { return __uint_as_float((unsigned)h << 16); }

struct SMpart { int hist[NB]; int scanv[NB + 1]; int gbase[NB]; int lcur[NB];
                unsigned stage[EPB]; };
struct SMbuild { int sbase[NB + 1]; int hist32[32]; int cur32[32];
                 unsigned stage[RSTRIDE]; };
union SMu {
    SMpart p;
    SMbuild b;
    float xs[16][128];
    float2 red2[3][64];
    float red1[3][64];
};

// ---- gemm1: 8 rows of Y = X[f32] @ W[128x128] -> bf16 ----
__device__ __forceinline__ void gemm1_block(const float* __restrict__ X,
                                            const float* __restrict__ W,
                                            unsigned short* __restrict__ Y,
                                            float (*xs)[128], int vb, int tid) {
    int row0 = vb * 8;
    for (int idx = tid; idx < 8 * 128; idx += 256) {
        int r = idx >> 7, k = idx & 127;
        xs[r][k] = X[(size_t)(row0 + r) * 128 + k];
    }
    __syncthreads();
    int ct = tid & 31, r = tid >> 5, c = ct * 4;
    float4 acc = make_float4(0.f, 0.f, 0.f, 0.f);
    #pragma unroll 8
    for (int k = 0; k < 128; ++k) {
        float xv = xs[r][k];
        float4 w = *reinterpret_cast<const float4*>(W + (size_t)k * 128 + c);
        acc.x += xv * w.x; acc.y += xv * w.y; acc.z += xv * w.z; acc.w += xv * w.w;
    }
    ushort4 o;
    o.x = f2bf(acc.x); o.y = f2bf(acc.y); o.z = f2bf(acc.z); o.w = f2bf(acc.w);
    *reinterpret_cast<ushort4*>(Y + (size_t)(row0 + r) * 128 + c) = o;
}

// ---- bf16-in GEMM: ROWS rows, NOUTc cols ----
template<int NOUTc, int ROWS>
__device__ __forceinline__ void gemm_bf_block(const unsigned short* __restrict__ Xb,
                                              const float* __restrict__ W,
                                              unsigned short* __restrict__ Y,
                                              float (*xs)[128], int vb, int tid) {
    int row0 = vb * ROWS;
    const unsigned* Xu = reinterpret_cast<const unsigned*>(Xb + (size_t)row0 * 128);
    for (int idx = tid; idx < ROWS * 64; idx += 256) {
        unsigned u = Xu[idx];
        int r = idx >> 6, kk = idx & 63;
        xs[r][kk * 2]     = bflo(u);
        xs[r][kk * 2 + 1] = bfhi(u);
    }
    __syncthreads();
    constexpr int COLT = NOUTc / 4;
    int ct = tid % COLT, r = tid / COLT, c = ct * 4;
    float4 acc = make_float4(0.f, 0.f, 0.f, 0.f);
    #pragma unroll 8
    for (int k = 0; k < 128; ++k) {
        float xv = xs[r][k];
        float4 w = *reinterpret_cast<const float4*>(W + (size_t)k * NOUTc + c);
        acc.x += xv * w.x; acc.y += xv * w.y; acc.z += xv * w.z; acc.w += xv * w.w;
    }
    ushort4 o;
    o.x = f2bf(acc.x); o.y = f2bf(acc.y); o.z = f2bf(acc.z); o.w = f2bf(acc.w);
    *reinterpret_cast<ushort4*>(Y + (size_t)(row0 + r) * NOUTc + c) = o;
}

// ---- partition: one block of EPB edges -> bucketed records ----
__device__ __forceinline__ void partition_block(const int* __restrict__ src,
                                                const int* __restrict__ dst,
                                                int* __restrict__ bcur,
                                                unsigned* __restrict__ edge_part,
                                                SMpart& p, int bid, int tid) {
    for (int i = tid; i < NB; i += 256) p.hist[i] = 0;
    __syncthreads();
    int gi = bid * EPB + tid * 8;
    unsigned rec[8];
    bool act = gi < NE;
    if (act) {
        int4 s0 = *reinterpret_cast<const int4*>(src + gi);
        int4 s1 = *reinterpret_cast<const int4*>(src + gi + 4);
        int4 d0 = *reinterpret_cast<const int4*>(dst + gi);
        int4 d1 = *reinterpret_cast<const int4*>(dst + gi + 4);
        rec[0] = ((unsigned)d0.x << 14) | (unsigned)s0.x;
        rec[1] = ((unsigned)d0.y << 14) | (unsigned)s0.y;
        rec[2] = ((unsigned)d0.z << 14) | (unsigned)s0.z;
        rec[3] = ((unsigned)d0.w << 14) | (unsigned)s0.w;
        rec[4] = ((unsigned)d1.x << 14) | (unsigned)s1.x;
        rec[5] = ((unsigned)d1.y << 14) | (unsigned)s1.y;
        rec[6] = ((unsigned)d1.z << 14) | (unsigned)s1.z;
        rec[7] = ((unsigned)d1.w << 14) | (unsigned)s1.w;
        #pragma unroll
        for (int k = 0; k < 8; ++k) atomicAdd(&p.hist[rec[k] >> 19], 1);
    }
    __syncthreads();
    if (tid < 64) {          // wave-0 exclusive scan of hist
        int carry = 0;
        for (int c = 0; c < NB; c += 64) {
            int idx = c + tid;
            int v = (idx < NB) ? p.hist[idx] : 0;
            int incl = v;
            #pragma unroll
            for (int d = 1; d < 64; d <<= 1) {
                int t = __shfl_up(incl, d, 64);
                if (tid >= d) incl += t;
            }
            if (idx < NB) p.scanv[idx] = carry + incl - v;
            carry += __shfl(incl, 63, 64);
        }
        if (tid == 0) p.scanv[NB] = carry;
    }
    __syncthreads();
    for (int bb = tid; bb < NB; bb += 256) {
        p.gbase[bb] = atomicAdd(&bcur[bb], p.hist[bb]);
        p.lcur[bb]  = p.scanv[bb];
    }
    __syncthreads();
    if (act) {
        #pragma unroll
        for (int k = 0; k < 8; ++k) {
            int bb = rec[k] >> 19;
            int pp = atomicAdd(&p.lcur[bb], 1);
            p.stage[pp] = rec[k];
        }
    }
    __syncthreads();
    int tot = p.scanv[NB];
    for (int i = tid; i < tot; i += 256) {
        unsigned r = p.stage[i];
        int bb = r >> 19;
        edge_part[bb * RSTRIDE + p.gbase[bb] + (i - p.scanv[bb])] = r;
    }
}

// ---- build: one bucket -> offs/inv_sqrt + node-sorted CSR (ushort src) ----
__device__ __forceinline__ void build_block(const unsigned* __restrict__ edge_part,
                                            const int* __restrict__ bcur,
                                            int* __restrict__ offs,
                                            float* __restrict__ inv_sqrt,
                                            unsigned short* __restrict__ edge_src,
                                            SMbuild& b, int bid, int tid) {
    if (tid < 64) {
        int carry = 0;
        for (int c = 0; c < NB; c += 64) {
            int idx = c + tid;
            int v = (idx < NB) ? bcur[idx] : 0;
            int incl = v;
            #pragma unroll
            for (int d = 1; d < 64; d <<= 1) {
                int t = __shfl_up(incl, d, 64);
                if (tid >= d) incl += t;
            }
            if (idx < NB) b.sbase[idx] = carry + incl - v;
            carry += __shfl(incl, 63, 64);
        }
    }
    if (tid < 32) b.hist32[tid] = 0;
    __syncthreads();
    int cnt = bcur[bid];
    int base = b.sbase[bid];
    const unsigned* part = edge_part + (size_t)bid * RSTRIDE;
    for (int k = tid; k < cnt; k += 256)
        atomicAdd(&b.hist32[(part[k] >> 14) & 31], 1);
    __syncthreads();
    if (tid < 32) {
        int v = b.hist32[tid];
        int incl = v;
        #pragma unroll
        for (int d = 1; d < 32; d <<= 1) {
            int t = __shfl_up(incl, d, 32);
            if (tid >= d) incl += t;
        }
        int excl = incl - v;
        b.cur32[tid] = excl;
        int node = bid * 32 + tid;
        if (node < NN) {
            offs[node] = base + excl;
            inv_sqrt[node] = rsqrtf((float)(v + 1));
        }
        if (bid == NB - 1 && tid == 0) offs[NN] = base + cnt;
    }
    __syncthreads();
    for (int k = tid; k < cnt; k += 256) {
        unsigned r = part[k];
        int pp = atomicAdd(&b.cur32[(r >> 14) & 31], 1);
        b.stage[pp] = r & 0x3FFFu;
    }
    __syncthreads();
    for (int k = tid; k < cnt; k += 256)
        edge_src[base + k] = (unsigned short)b.stage[k];
}

// ---- agg128: one node, 4 waves (quarter edge-chains); bf16 out ----
__device__ __forceinline__ void agg128_node(const unsigned short* __restrict__ H,
                                            unsigned* __restrict__ Aout,
                                            float bx, float by,
                                            const int* __restrict__ offs,
                                            const float* __restrict__ isqv,
                                            const unsigned short* __restrict__ esrc,
                                            float2 (*red)[64], int node,
                                            int lane, int wv) {
    int s = offs[node], e = offs[node + 1];
    int deg = e - s;
    int qlen = (((deg + 3) >> 2) + 3) & ~3;
    int js = s + wv * qlen;
    int je = js + qlen;
    if (js > e) js = e;
    if (je > e) je = e;
    int col = lane * 2;
    float2 acc = make_float2(0.f, 0.f);
    int j = js;
    for (; j + 4 <= je; j += 4) {
        int s0 = esrc[j], s1 = esrc[j + 1], s2 = esrc[j + 2], s3 = esrc[j + 3];
        float w0 = isqv[s0], w1 = isqv[s1], w2 = isqv[s2], w3 = isqv[s3];
        unsigned u0 = *reinterpret_cast<const unsigned*>(H + (size_t)s0 * 128 + col);
        unsigned u1 = *reinterpret_cast<const unsigned*>(H + (size_t)s1 * 128 + col);
        unsigned u2 = *reinterpret_cast<const unsigned*>(H + (size_t)s2 * 128 + col);
        unsigned u3 = *reinterpret_cast<const unsigned*>(H + (size_t)s3 * 128 + col);
        acc.x += w0 * bflo(u0); acc.y += w0 * bfhi(u0);
        acc.x += w1 * bflo(u1); acc.y += w1 * bfhi(u1);
        acc.x += w2 * bflo(u2); acc.y += w2 * bfhi(u2);
        acc.x += w3 * bflo(u3); acc.y += w3 * bfhi(u3);
    }
    for (; j < je; ++j) {
        int s0 = esrc[j];
        float w0 = isqv[s0];
        unsigned u0 = *reinterpret_cast<const unsigned*>(H + (size_t)s0 * 128 + col);
        acc.x += w0 * bflo(u0); acc.y += w0 * bfhi(u0);
    }
    if (wv) red[wv - 1][lane] = acc;
    __syncthreads();
    if (!wv) {
        acc.x += red[0][lane].x + red[1][lane].x + red[2][lane].x;
        acc.y += red[0][lane].y + red[1][lane].y + red[2][lane].y;
        float isq = isqv[node];
        unsigned uv = *reinterpret_cast<const unsigned*>(H + (size_t)node * 128 + col);
        float self = isq * isq;
        float ox = fmaxf(acc.x * isq + self * bflo(uv) + bx, 0.f);
        float oy = fmaxf(acc.y * isq + self * bfhi(uv) + by, 0.f);
        Aout[(size_t)node * 64 + lane] = (unsigned)f2bf(ox) | ((unsigned)f2bf(oy) << 16);
    }
}

// ---- agg64: one node, 4 waves; f32 out, no relu ----
__device__ __forceinline__ void agg64_node(const unsigned short* __restrict__ H,
                                           float* __restrict__ out, float b3v,
                                           const int* __restrict__ offs,
                                           const float* __restrict__ isqv,
                                           const unsigned short* __restrict__ esrc,
                                           float (*red)[64], int node,
                                           int lane, int wv) {
    int s = offs[node], e = offs[node + 1];
    int deg = e - s;
    int qlen = (((deg + 3) >> 2) + 3) & ~3;
    int js = s + wv * qlen;
    int je = js + qlen;
    if (js > e) js = e;
    if (je > e) je = e;
    float acc = 0.f;
    int j = js;
    for (; j + 4 <= je; j += 4) {
        int s0 = esrc[j], s1 = esrc[j + 1], s2 = esrc[j + 2], s3 = esrc[j + 3];
        float w0 = isqv[s0], w1 = isqv[s1], w2 = isqv[s2], w3 = isqv[s3];
        acc += w0 * bf1(H[(size_t)s0 * 64 + lane]);
        acc += w1 * bf1(H[(size_t)s1 * 64 + lane]);
        acc += w2 * bf1(H[(size_t)s2 * 64 + lane]);
        acc += w3 * bf1(H[(size_t)s3 * 64 + lane]);
    }
    for (; j < je; ++j) {
        int s0 = esrc[j];
        acc += isqv[s0] * bf1(H[(size_t)s0 * 64 + lane]);
    }
    if (wv) red[wv - 1][lane] = acc;
    __syncthreads();
    if (!wv) {
        acc += red[0][lane] + red[1][lane] + red[2][lane];
        float isq = isqv[node];
        float hv = bf1(H[(size_t)node * 64 + lane]);
        out[(size_t)node * 64 + lane] = acc * isq + isq * isq * hv + b3v;
    }
}

// ======================= kernels =======================
__global__ __launch_bounds__(256) void part_gemm1_kernel(
        const int* __restrict__ src, const int* __restrict__ dst,
        int* __restrict__ bcur, unsigned* __restrict__ edge_part,
        const float* __restrict__ X, const float* __restrict__ W,
        unsigned short* __restrict__ Y) {
    __shared__ SMu sm;
    int tid = threadIdx.x;
    if (blockIdx.x >= NB) {
        gemm1_block(X, W, Y, sm.xs, blockIdx.x - NB, tid);
        return;
    }
    partition_block(src, dst, bcur, edge_part, sm.p, blockIdx.x, tid);
}

__global__ __launch_bounds__(256) void build_kernel(
        const unsigned* __restrict__ edge_part, const int* __restrict__ bcur,
        int* __restrict__ offs, float* __restrict__ inv_sqrt,
        unsigned short* __restrict__ edge_src) {
    __shared__ SMu sm;
    build_block(edge_part, bcur, offs, inv_sqrt, edge_src, sm.b,
                blockIdx.x, threadIdx.x);
}

__global__ __launch_bounds__(256) void agg128_kernel(
        const unsigned short* __restrict__ H, const unsigned short* __restrict__ esrc,
        const int* __restrict__ offs, const float* __restrict__ inv_sqrt,
        const float* __restrict__ bias, unsigned* __restrict__ Aout) {
    __shared__ SMu sm;
    int tid = threadIdx.x, lane = tid & 63, wv = tid >> 6;
    int col = lane * 2;
    agg128_node(H, Aout, bias[col], bias[col + 1], offs, inv_sqrt, esrc,
                sm.red2, blockIdx.x, lane, wv);
}

__global__ __launch_bounds__(256) void agg64_kernel(
        const unsigned short* __restrict__ H, const unsigned short* __restrict__ esrc,
        const int* __restrict__ offs, const float* __restrict__ inv_sqrt,
        const float* __restrict__ bias, float* __restrict__ out) {
    __shared__ SMu sm;
    int tid = threadIdx.x, lane = tid & 63, wv = tid >> 6;
    agg64_node(H, out, bias[lane], offs, inv_sqrt, esrc,
               sm.red1, blockIdx.x, lane, wv);
}

template<int N>
__global__ __launch_bounds__(256) void gemm_bf_kernel(
        const unsigned short* __restrict__ X, const float* __restrict__ W,
        unsigned short* __restrict__ Y) {
    __shared__ SMu sm;
    gemm_bf_block<N, 256 / (N / 4)>(X, W, Y, sm.xs, blockIdx.x, threadIdx.x);
}

extern "C" void kernel_launch(void* const* d_in, const int* in_sizes, int n_in,
                              void* d_out, int out_size, void* d_ws, size_t ws_size,
                              hipStream_t stream) {
    const float* x  = (const float*)d_in[0];
    const int*   ei = (const int*)d_in[1];
    const float* W1 = (const float*)d_in[2];
    const float* b1 = (const float*)d_in[3];
    const float* W2 = (const float*)d_in[4];
    const float* b2 = (const float*)d_in[5];
    const float* W3 = (const float*)d_in[6];
    const float* b3 = (const float*)d_in[7];
    float* out = (float*)d_out;

    const int* src = ei;
    const int* dst = ei + NE;

    char* ws = (char*)d_ws;
    int*            bcur      = (int*)(ws);                        // 1,252 B
    float*          inv_sqrt  = (float*)(ws + 4096);               // 40,000 B
    int*            offs      = (int*)(ws + 45056);                // 40,004 B
    unsigned*       edge_part = (unsigned*)(ws + 86016);           // 3,365,376 B
    unsigned short* edge_src  = (unsigned short*)(ws + 3451392);   // 1,280,000 B
    unsigned short* T1        = (unsigned short*)(ws + 6011392);   // 2,560,000 B
    unsigned short* A         = (unsigned short*)(ws + 8571392);   // 2,560,000 B
    unsigned short* T2        = (unsigned short*)edge_part;        // alias (dead after build)
    unsigned short* T3        = T1;                                // alias (dead after agg1)

    hipMemsetAsync(bcur, 0, NB * sizeof(int), stream);
    part_gemm1_kernel<<<NB + G1B, 256, 0, stream>>>(src, dst, bcur, edge_part,
                                                    x, W1, T1);
    build_kernel<<<NB, 256, 0, stream>>>(edge_part, bcur, offs, inv_sqrt, edge_src);
    agg128_kernel<<<NN, 256, 0, stream>>>(T1, edge_src, offs, inv_sqrt, b1,
                                          (unsigned*)A);
    gemm_bf_kernel<128><<<NN / 8, 256, 0, stream>>>(A, W2, T2);
    agg128_kernel<<<NN, 256, 0, stream>>>(T2, edge_src, offs, inv_sqrt, b2,
                                          (unsigned*)A);
    gemm_bf_kernel<64><<<NN / 16, 256, 0, stream>>>(A, W3, T3);
    agg64_kernel<<<NN, 256, 0, stream>>>(T3, edge_src, offs, inv_sqrt, b3, out);
}